// Round 1
// baseline (657.881 us; speedup 1.0000x reference)
//
#include <hip/hip_runtime.h>
#include <hip/hip_bf16.h>

typedef __bf16 bf16x8 __attribute__((ext_vector_type(8)));
typedef __bf16 bf16x4 __attribute__((ext_vector_type(4)));
typedef float  f32x16 __attribute__((ext_vector_type(16)));

#define BM 128           // batch rows per block (4 N-tiles of 32)
#define S  520           // bf16 elems per LDS activation row (512 + 8)
#define SF 260           // f32 elems per LDS row for out staging (same 1040 B)
#define NT 4             // batch tiles (of 32 rows) per wave

// ---------------- weight prepack ----------------
// Transposed formulation: A-operand = W^T for v_mfma_f32_32x32x16_bf16.
// A[m][k]: m = lane&31 (out-feature), k = (lane>>5)*8 + j.
// Packed unit u = unitBase[w] + ((mt*Kc + kc)*64 + lane), Kc = K/16; 8 bf16:
//   elem j = W[kc*16 + (lane>>5)*8 + j][mt*32 + (lane&31)]
struct PrepParams {
    const float* src[9];
    int Kt[9];       // K/32
    int Mg[9];       // N/128 (col groups)
    int N[9];
    int blkEnd[9];
    int unitBase[9];
};

__global__ void __launch_bounds__(256)
prep_weights(PrepParams p, uint4* __restrict__ dst) {
    __shared__ float tile[32][128];
    int b = blockIdx.x;
    int w = 0;
    while (b >= p.blkEnd[w]) ++w;
    int local = b - ((w == 0) ? 0 : p.blkEnd[w - 1]);
    int mgc = p.Mg[w];
    int kt = local / mgc;
    int mg = local - kt * mgc;
    const float* src = p.src[w];
    int N = p.N[w];
    int Kc = p.Kt[w] * 2;
    int t = threadIdx.x;

    int row0 = kt * 32, col0 = mg * 128;
#pragma unroll
    for (int i = 0; i < 4; ++i) {
        int e4 = t + i * 256;            // 1024 float4 in 32x128 tile
        int r = e4 >> 5;
        int c4 = e4 & 31;
        float4 v = *(const float4*)&src[(size_t)(row0 + r) * N + col0 + c4 * 4];
        *(float4*)&tile[r][c4 * 4] = v;
    }
    __syncthreads();

#pragma unroll
    for (int rep = 0; rep < 2; ++rep) {
        int ul = t + rep * 256;          // 512 units per block
        int lane = ul & 63;
        int kcl = (ul >> 6) & 1;
        int mtl = ul >> 7;               // 0..3
        int gUnit = p.unitBase[w] +
                    ((mg * 4 + mtl) * Kc + (kt * 2 + kcl)) * 64 + lane;
        int lr = kcl * 16 + ((lane >> 5) << 3);
        int lc = mtl * 32 + (lane & 31);
        alignas(16) unsigned short u8[8];
#pragma unroll
        for (int j = 0; j < 8; ++j)
            u8[j] = __builtin_bit_cast(unsigned short, (__bf16)tile[lr + j][lc]);
        dst[gUnit] = *(const uint4*)u8;
    }
}

// ---------------- fused MLP ----------------
struct MlpParams {
    const float* X[3];
    const unsigned short* Wp[3];
    const float* B1[3];
    const float* B2[3];
    const float* B3[3];
    int dIn[3];
    int Nt[3];
    int rowOff[3];
    int blkStart[3];
};

__device__ __forceinline__ float sigmoidf(float z) {
    return __builtin_amdgcn_rcpf(
        1.0f + __builtin_amdgcn_exp2f(-1.442695040888963f * z));
}

// Transposed layer: D[feature][batch] = W^T (A, from packed global) x
// H (B, from LDS rows [batch][feature]). Wave owns MT feature-tiles (32 each)
// x NT batch-tiles. C/D: batchcol = lane&31,
// featrow = (reg&3) + 8*(reg>>2) + 4*(lane>>5)  -> 4 consecutive features
// per reg-quad => packed b64 LDS writes / float4 out writes.
//
// KC is compile-time: the kc loop fully unrolls and A-fragments rotate
// through a depth-4 register prefetch buffer with STATIC indices, so the
// compiler emits counted vmcnt waits (8 outstanding 1KB loads/wave vs 2).
template <int KC, int MT, bool TO_LDS>
__device__ __forceinline__ void layer(
    unsigned short* __restrict__ buf,
    const unsigned short* __restrict__ W,
    const float* __restrict__ bias,
    int wave, int lane)
{
    const int half = lane >> 5;
    const int lr = lane & 31;

    f32x16 acc[NT][MT];
#pragma unroll
    for (int n = 0; n < NT; ++n)
#pragma unroll
        for (int m = 0; m < MT; ++m)
#pragma unroll
            for (int e = 0; e < 16; ++e)
                acc[n][m][e] = 0.0f;

    const unsigned short* bp = buf + lr * S + half * 8;
    const unsigned short* ap = W + (size_t)wave * MT * KC * 512 + lane * 8;

    // depth-4 A prefetch (KC >= 4 in all instantiations)
    bf16x8 aPf[4][MT];
#pragma unroll
    for (int p = 0; p < 4; ++p)
#pragma unroll
        for (int m = 0; m < MT; ++m)
            aPf[p][m] = *(const bf16x8*)(ap + ((size_t)m * KC + p) * 512);

#pragma unroll
    for (int kc = 0; kc < KC; ++kc) {
        bf16x8 b[NT];
#pragma unroll
        for (int n = 0; n < NT; ++n)
            b[n] = *(const bf16x8*)(bp + (size_t)n * 32 * S + kc * 16);
#pragma unroll
        for (int m = 0; m < MT; ++m)
#pragma unroll
            for (int n = 0; n < NT; ++n)
                acc[n][m] = __builtin_amdgcn_mfma_f32_32x32x16_bf16(
                    aPf[kc & 3][m], b[n], acc[n][m], 0, 0, 0);
        if (kc + 4 < KC) {
#pragma unroll
            for (int m = 0; m < MT; ++m)
                aPf[kc & 3][m] =
                    *(const bf16x8*)(ap + ((size_t)m * KC + (kc + 4)) * 512);
        }
    }

    __syncthreads();   // all waves' B-reads done before in-place overwrite

#pragma unroll
    for (int m = 0; m < MT; ++m) {
        int mt = wave * MT + m;
#pragma unroll
        for (int g = 0; g < 4; ++g) {
            int f0 = mt * 32 + g * 8 + half * 4;   // 4 consecutive features
            float4 bv = *(const float4*)(bias + f0);
#pragma unroll
            for (int n = 0; n < NT; ++n) {
                int r = n * 32 + lr;
                float s0 = sigmoidf(acc[n][m][g * 4 + 0] + bv.x);
                float s1 = sigmoidf(acc[n][m][g * 4 + 1] + bv.y);
                float s2 = sigmoidf(acc[n][m][g * 4 + 2] + bv.z);
                float s3 = sigmoidf(acc[n][m][g * 4 + 3] + bv.w);
                if constexpr (TO_LDS) {
                    bf16x4 h = {(__bf16)s0, (__bf16)s1, (__bf16)s2, (__bf16)s3};
                    *(bf16x4*)(buf + r * S + f0) = h;      // packed b64
                } else {
                    float* fb = (float*)buf;
                    *(float4*)(fb + r * SF + f0) =
                        make_float4(s0, s1, s2, s3);        // b128
                }
            }
        }
    }
}

__global__ void __launch_bounds__(512, 2)   // 1 block/CU (LDS 133 KB), 256-VGPR budget
mlp_fused(MlpParams p, float* __restrict__ out) {
    extern __shared__ unsigned short buf[];

    // bijective chunked XCD swizzle (m204): contiguous block ranges per XCD
    // -> each XCD's L2 mostly serves one type's ~1MB weight set.
    int nwg = gridDim.x;
    int bid = blockIdx.x;
    int q = nwg >> 3, r8 = nwg & 7;
    int xcd = bid & 7, lid = bid >> 3;
    int b = (xcd < r8 ? xcd * (q + 1) : r8 * (q + 1) + (xcd - r8) * q) + lid;

    int t = (b >= p.blkStart[1]) + (b >= p.blkStart[2]);
    int blk = b - p.blkStart[t];
    int dIn = p.dIn[t];
    int Nt = p.Nt[t];
    int row0 = blk * BM;
    const float* X = p.X[t];
    const unsigned short* W1 = p.Wp[t];
    const unsigned short* W2 = W1 + dIn * 512;
    const unsigned short* W3 = W2 + 512 * 512;

    int tid = threadIdx.x;
    int wave = tid >> 6;
    int lane = tid & 63;

    // ---- stage X (fp32 global -> bf16 LDS rows [batch][feat]) ----
    int d4 = dIn >> 2;               // float4 per row (16/32/64)
    int s4 = 31 - __clz(d4);
    int nf4 = BM * d4;
    for (int i = tid; i < nf4; i += 512) {
        int r = i >> s4;
        int c4 = i & (d4 - 1);
        int grow = row0 + r;
        float4 v = make_float4(0.f, 0.f, 0.f, 0.f);
        if (grow < Nt) v = ((const float4*)X)[(size_t)grow * d4 + c4];
        ushort4 u;
        u.x = __builtin_bit_cast(unsigned short, (__bf16)v.x);
        u.y = __builtin_bit_cast(unsigned short, (__bf16)v.y);
        u.z = __builtin_bit_cast(unsigned short, (__bf16)v.z);
        u.w = __builtin_bit_cast(unsigned short, (__bf16)v.w);
        *(ushort4*)(buf + r * S + c4 * 4) = u;
    }
    __syncthreads();

    // L1: X -> H1 in place (512 feats); KC = dIn/16 is compile-time per type
    if (t == 0)      layer< 4, 2, true>(buf, W1, p.B1[t], wave, lane);
    else if (t == 1) layer< 8, 2, true>(buf, W1, p.B1[t], wave, lane);
    else             layer<16, 2, true>(buf, W1, p.B1[t], wave, lane);
    __syncthreads();
    // L2: H1 -> H2 in place (512 feats)
    layer<32, 2, true>(buf, W2, p.B2[t], wave, lane);
    __syncthreads();
    // L3: H2 -> f32 staging (256 feats, 1 mtile/wave)
    layer<32, 1, false>(buf, W3, p.B3[t], wave, lane);
    __syncthreads();

    // ---- coalesced output store: 128 rows x 256 f32, full 1KB rows ----
    const float* fb = (const float*)buf;
    float* gOut = out + (size_t)(p.rowOff[t] + row0) * 256;
    for (int i = tid; i < BM * 64; i += 512) {   // 8192 float4
        int r = i >> 6;
        int c4 = i & 63;
        if (row0 + r < Nt)
            *(float4*)(gOut + r * 256 + c4 * 4) =
                *(const float4*)(fb + r * SF + c4 * 4);
    }
}

// ---------------- launch ----------------
extern "C" void kernel_launch(void* const* d_in, const int* in_sizes, int n_in,
                              void* d_out, int out_size, void* d_ws, size_t ws_size,
                              hipStream_t stream) {
    const int IN0[3] = {64, 128, 256};
    const int CNT[3] = {100000, 80000, 60000};

    // ---- prepack weights into ws (bf16, A-fragment-ordered for 32x32x16) ----
    PrepParams pp;
    int blocks = 0, ubase = 0;
    for (int t = 0; t < 3; ++t) {
        int Ks[3] = {IN0[t], 512, 512};
        int Ns[3] = {512, 512, 256};
        for (int l = 0; l < 3; ++l) {
            int w = t * 3 + l;
            pp.src[w] = (const float*)d_in[4 + t * 6 + l * 2];
            pp.Kt[w] = Ks[l] >> 5;
            pp.Mg[w] = Ns[l] >> 7;
            pp.N[w] = Ns[l];
            pp.unitBase[w] = ubase;
            blocks += pp.Kt[w] * pp.Mg[w];
            pp.blkEnd[w] = blocks;
            ubase += (Ks[l] * Ns[l]) >> 3;
        }
    }
    prep_weights<<<dim3(blocks), dim3(256), 0, stream>>>(pp, (uint4*)d_ws);

    // ---- fused MLP ----
    MlpParams mp;
    int woff = 0, roff = 0, boff = 0;
    for (int t = 0; t < 3; ++t) {
        mp.X[t] = (const float*)d_in[t];
        mp.Wp[t] = (const unsigned short*)d_ws + woff;
        mp.B1[t] = (const float*)d_in[4 + t * 6 + 1];
        mp.B2[t] = (const float*)d_in[4 + t * 6 + 3];
        mp.B3[t] = (const float*)d_in[4 + t * 6 + 5];
        mp.dIn[t] = IN0[t];
        mp.Nt[t] = CNT[t];
        mp.rowOff[t] = roff;
        mp.blkStart[t] = boff;
        woff += IN0[t] * 512 + 512 * 512 + 512 * 256;
        roff += CNT[t];
        boff += (CNT[t] + BM - 1) / BM;
    }
    size_t lds = (size_t)BM * S * sizeof(unsigned short);   // 133,120 B
    mlp_fused<<<dim3(boff), dim3(512), lds, stream>>>(mp, (float*)d_out);
}